// Round 2
// baseline (769.557 us; speedup 1.0000x reference)
//
#include <hip/hip_runtime.h>
#include <hip/hip_bf16.h>

// Problem constants (match reference)
#define BB   8
#define HH   8
#define NN   65536
#define DD   128
#define BDIM 64
#define KK   32

// All inputs/outputs are float32 per the reference dtypes.

// Workspace layout (float units)
#define OFF_SIMW 0u                       // B*H*N = 4194304
#define OFF_SIMR (OFF_SIMW + 4194304u)    // 4194304
#define OFF_NWK  (OFF_SIMR + 4194304u)    // 8192
#define OFF_NRK  (OFF_NWK + 8192u)        // 8192
#define OFF_CV   (OFF_NRK + 8192u)        // 8192
#define OFF_WIDX (OFF_CV + 8192u)         // 2048 (int)
#define OFF_WVAL (OFF_WIDX + 2048u)       // 2048
#define OFF_RIDX (OFF_WVAL + 2048u)       // 2048 (int)
#define OFF_RVAL (OFF_RIDX + 2048u)       // 2048
#define OFF_M2U  (OFF_RVAL + 2048u)       // B*256*D = 262144
#define OFF_RPH  (OFF_M2U + 262144u)      // 8192
// total = 8691712 floats = ~34.8 MB

// native clang vector type: __builtin_nontemporal_load needs this
// (HIP's float4 is a class and is rejected by the builtin).
typedef float f32x4 __attribute__((ext_vector_type(4)));

// ---- helpers ----
__device__ __forceinline__ float brsum128(float v, float* sred, int tid) {
  #pragma unroll
  for (int o = 32; o > 0; o >>= 1) v += __shfl_xor(v, o);
  __syncthreads();
  if ((tid & 63) == 0) sred[tid >> 6] = v;
  __syncthreads();
  return sred[0] + sred[1];
}

// ---- K1: normalize keys (fold beta), MLP cvals, zero rph ----
__global__ __launch_bounds__(128) void k1_setup(
    const float* __restrict__ wkeys, const float* __restrict__ rkeys,
    const float* __restrict__ wvals,
    const float* __restrict__ beta_r, const float* __restrict__ beta_w,
    const float* __restrict__ W_b1, const float* __restrict__ b_b1,
    const float* __restrict__ W_b2, const float* __restrict__ b_b2,
    float* __restrict__ nwk, float* __restrict__ nrk,
    float* __restrict__ cvals, float* __restrict__ rph) {
  int g = blockIdx.x;      // b*H + h, 0..63
  int d = threadIdx.x;     // 0..127
  __shared__ float sred[2];
  __shared__ float wv_s[DD];
  __shared__ float hid[BDIM];

  rph[g * DD + d] = 0.f;

  float wk = wkeys[g * DD + d];
  float rk = rkeys[g * DD + d];
  float wv = wvals[g * DD + d];
  wv_s[d] = wv;

  float s = brsum128(wk * wk, sred, d);
  nwk[g * DD + d] = wk / fmaxf(sqrtf(s), 1e-12f) * beta_w[g];
  s = brsum128(rk * rk, sred, d);
  nrk[g * DD + d] = rk / fmaxf(sqrtf(s), 1e-12f) * beta_r[g];

  __syncthreads();
  if (d < BDIM) {
    float a = b_b1[d];
    #pragma unroll 4
    for (int dd = 0; dd < DD; ++dd) a += wv_s[dd] * W_b1[dd * BDIM + d];
    hid[d] = a * 0.5f * (1.f + erff(a * 0.70710678118654752f));  // exact gelu
  }
  __syncthreads();
  float c = b_b2[d];
  #pragma unroll 4
  for (int j = 0; j < BDIM; ++j) c += hid[j] * W_b2[j * DD + d];
  cvals[g * DD + d] = c;
}

// ---- K2: big pass over memory: row norms + 16 dots -> simw, simr ----
// Per-lane row streaming, but consume 128B line-groups with 8 back-to-back
// float4 loads so every fetched line is fully used while in flight.
// Nontemporal loads: the 256MB memory stream must not evict the 33.5MB of
// sims from L2/LLC (they are re-read twice by the topk passes).
__global__ __launch_bounds__(256) void k2_sims(
    const float* __restrict__ mem,
    const float* __restrict__ nwk, const float* __restrict__ nrk,
    float* __restrict__ simw, float* __restrict__ simr) {
  int blk = blockIdx.x;          // 0..2047
  int b   = blk >> 8;
  int n   = ((blk & 255) << 8) + threadIdx.x;   // row in [0,N)
  const f32x4* rowp = (const f32x4*)(mem + ((size_t)b * NN + n) * DD);

  float dw[HH] = {0,0,0,0,0,0,0,0};
  float dr[HH] = {0,0,0,0,0,0,0,0};
  float nw = 0.f, nr = 0.f;
  const float* kw = nwk + b * HH * DD;   // block-uniform -> scalar loads
  const float* kr = nrk + b * HH * DD;

  for (int g = 0; g < 4; ++g) {          // 4 groups x 128B
    f32x4 q[8];
    #pragma unroll
    for (int i = 0; i < 8; ++i) q[i] = __builtin_nontemporal_load(rowp + g * 8 + i);
    #pragma unroll
    for (int i = 0; i < 8; ++i) {
      #pragma unroll
      for (int e = 0; e < 4; ++e) {
        float xv = q[i][e];
        float xr = xv + 1e-8f;
        nw += xv * xv;
        nr += xr * xr;
        int d = g * 32 + i * 4 + e;
        #pragma unroll
        for (int h = 0; h < HH; ++h) {
          dw[h] += xv * kw[h * DD + d];
          dr[h] += xr * kr[h * DD + d];
        }
      }
    }
  }
  float riw = 1.f / fmaxf(sqrtf(nw), 1e-12f);
  float rir = 1.f / fmaxf(sqrtf(nr), 1e-12f);
  #pragma unroll
  for (int h = 0; h < HH; ++h) {
    simw[(size_t)(b * HH + h) * NN + n] = dw[h] * riw;
    simr[(size_t)(b * HH + h) * NN + n] = dr[h] * rir;
  }
}

// ---- K3/K5: exact top-32 + softmax via exponent-bucket histogram select ----
// No min/max pass: bucket = top 12 bits of the ordered-float bit pattern
// (sign+exp+3 mantissa). Monotonic and scale-invariant, so the threshold
// bucket of a Gaussian-tail top-32 holds only ~tens of values.
// 1024 threads (16 waves/CU) to hide the L2/LLC latency of the 2 scans.
#define NBKT 4096
#define MAXC 4096
__global__ __launch_bounds__(1024) void k_topk(
    const float* __restrict__ sims, int* __restrict__ oidx, float* __restrict__ oval) {
  int blk = blockIdx.x;          // (b*H+h), 0..63
  int tid = threadIdx.x;
  const float4* s4 = (const float4*)(sims + (size_t)blk * NN);
  __shared__ unsigned hist[NBKT];
  __shared__ unsigned segsum[64];
  __shared__ float cv[MAXC];
  __shared__ int   ci[MAXC];
  __shared__ int   sthr, scnt;
  __shared__ float selv[KK];
  __shared__ int   seli[KK];

  #pragma unroll
  for (int i = tid; i < NBKT; i += 1024) hist[i] = 0u;
  if (tid == 0) scnt = 0;
  __syncthreads();

  // pass A: histogram on ordered-float top-12-bit buckets
  #pragma unroll 4
  for (int i = tid; i < NN / 4; i += 1024) {
    float4 v = s4[i];
    float xs[4] = {v.x, v.y, v.z, v.w};
    #pragma unroll
    for (int e = 0; e < 4; ++e) {
      unsigned u = __float_as_uint(xs[e]);
      u = (u & 0x80000000u) ? ~u : (u | 0x80000000u);
      atomicAdd(&hist[u >> 20], 1u);
    }
  }
  __syncthreads();

  // threshold: cumulative count from the top; two-level scan.
  // rotated reads: lane t reads hist[t*64 + ((j+t)&63)] -> all banks hit,
  // avoids the 64-way conflict of straight stride-64 segment sums.
  if (tid < 64) {
    unsigned ssum = 0;
    int base = tid << 6;
    #pragma unroll
    for (int j = 0; j < 64; ++j) ssum += hist[base + ((j + tid) & 63)];
    segsum[tid] = ssum;
  }
  __syncthreads();
  if (tid == 0) {
    unsigned acc = 0;
    int sg = 63;
    while (sg > 0 && acc + segsum[sg] < KK) { acc += segsum[sg]; --sg; }
    int t = (sg << 6) + 63;
    while (t > (sg << 6) && acc + hist[t] < KK) { acc += hist[t]; --t; }
    sthr = t;
  }
  __syncthreads();

  // pass B: compact candidates (bucket >= threshold -> superset of top-32)
  int thr = sthr;
  #pragma unroll 2
  for (int i = tid; i < NN / 4; i += 1024) {
    float4 v = s4[i];
    float xs[4] = {v.x, v.y, v.z, v.w};
    #pragma unroll
    for (int e = 0; e < 4; ++e) {
      float vv = xs[e];
      unsigned u = __float_as_uint(vv);
      u = (u & 0x80000000u) ? ~u : (u | 0x80000000u);
      if ((int)(u >> 20) >= thr) {
        int p = atomicAdd(&scnt, 1);
        if (p < MAXC) { cv[p] = vv; ci[p] = i * 4 + e; }
      }
    }
  }
  __syncthreads();
  int nc = min(scnt, MAXC);

  // 32 exact extractions by wave 0 only: 64-bit key = (ordered(v) << 32) | ~idx
  // (value desc, index asc — matches lax.top_k), shuffle-reduced, no barriers.
  if (tid < 64) {
    for (int k = 0; k < KK; ++k) {
      unsigned long long best = 0ull, lbest = 0ull;
      int lj = -1;
      for (int j = tid; j < nc; j += 64) {
        float v = cv[j];
        unsigned u = __float_as_uint(v);
        u = (u & 0x80000000u) ? ~u : (u | 0x80000000u);
        unsigned long long key = ((unsigned long long)u << 32) | (unsigned)(~(unsigned)ci[j]);
        if (key > lbest) { lbest = key; lj = j; }
      }
      best = lbest;
      #pragma unroll
      for (int o = 32; o > 0; o >>= 1) {
        unsigned long long t = __shfl_xor(best, o);
        if (t > best) best = t;
      }
      if (lbest == best && lj >= 0) cv[lj] = -1e30f;   // owner removes winner
      if (tid == 0) {
        unsigned u = (unsigned)(best >> 32);
        float v = (u & 0x80000000u) ? __uint_as_float(u & 0x7fffffffu) : __uint_as_float(~u);
        selv[k] = v;
        seli[k] = (int)~(unsigned)(best & 0xffffffffu);
      }
    }
    if (tid == 0) {
      float m0 = selv[0], ssum = 0.f;   // selv descending -> selv[0] is max
      float es[KK];
      #pragma unroll
      for (int k = 0; k < KK; ++k) { es[k] = expf(selv[k] - m0); ssum += es[k]; }
      float inv = 1.f / ssum;
      #pragma unroll
      for (int k = 0; k < KK; ++k) {
        oidx[blk * KK + k] = seli[k];
        oval[blk * KK + k] = es[k] * inv;
      }
    }
  }
}

// ---- K4: apply erase/add to touched rows, store unit rows, patch simr ----
__global__ __launch_bounds__(128) void k4_write(
    const float* __restrict__ mem, const float* __restrict__ erase,
    const float* __restrict__ adg,
    const int* __restrict__ widx, const float* __restrict__ wval,
    const float* __restrict__ cvals, const float* __restrict__ nrk,
    float* __restrict__ mem2u, float* __restrict__ simr) {
  int b  = blockIdx.x >> 8;
  int sl = blockIdx.x & 255;          // slot in b's write list (h*32+k)
  int d  = threadIdx.x;
  __shared__ int   swi[256];
  __shared__ float swv[256];
  __shared__ float sred[2 * 9];

  swi[d]       = widx[b * 256 + d];
  swi[d + 128] = widx[b * 256 + d + 128];
  swv[d]       = wval[b * 256 + d];
  swv[d + 128] = wval[b * 256 + d + 128];
  __syncthreads();

  int n = swi[sl];
  for (int j = 0; j < sl; ++j) if (swi[j] == n) return;  // uniform: whole block

  float E = 0.f, addd = 0.f;
  #pragma unroll
  for (int h = 0; h < HH; ++h) {
    float er = erase[b * HH + h];
    float ag = adg[b * HH + h];
    float aw = 0.f;
    #pragma unroll 4
    for (int k = 0; k < KK; ++k) {
      int j = h * KK + k;
      if (swi[j] == n) { float wv = swv[j]; E += wv * er; aw += wv; }
    }
    addd += aw * ag * cvals[(b * HH + h) * DD + d];
  }
  float mval = mem[((size_t)b * NN + n) * DD + d];
  float v = mval * (1.f - E * 0.125f) + addd * 0.125f + 1e-8f;

  // one fused 9-value reduction: [0]=v^2, [1..8]=nrk_h[d]*v
  float r[9];
  r[0] = v * v;
  #pragma unroll
  for (int h = 0; h < HH; ++h) r[1 + h] = nrk[(b * HH + h) * DD + d] * v;
  #pragma unroll
  for (int o = 32; o > 0; o >>= 1) {
    #pragma unroll
    for (int i = 0; i < 9; ++i) r[i] += __shfl_xor(r[i], o);
  }
  if ((d & 63) == 0) {
    int w = d >> 6;
    #pragma unroll
    for (int i = 0; i < 9; ++i) sred[w * 9 + i] = r[i];
  }
  __syncthreads();
  float S    = sred[0] + sred[9];
  float rinv = 1.f / fmaxf(sqrtf(S), 1e-12f);
  mem2u[(size_t)(b * 256 + sl) * DD + d] = v * rinv;
  if (d < HH) simr[(size_t)(b * HH + d) * NN + n] = (sred[1 + d] + sred[9 + 1 + d]) * rinv;
}

// ---- K6: gather read rows -> rph (atomic accumulate) ----
__global__ __launch_bounds__(128) void k6_gather(
    const float* __restrict__ mem, const float* __restrict__ decay,
    const int* __restrict__ widx, const int* __restrict__ ridx,
    const float* __restrict__ rval, const float* __restrict__ mem2u,
    float* __restrict__ rph) {
  int b   = blockIdx.x >> 8;
  int rem = blockIdx.x & 255;    // h*32+k
  int d   = threadIdx.x;
  __shared__ int swi[256];
  __shared__ float sred[2];
  swi[d]       = widx[b * 256 + d];
  swi[d + 128] = widx[b * 256 + d + 128];
  __syncthreads();

  int n   = ridx[b * HH * KK + rem];
  float w = rval[b * HH * KK + rem];
  float sc = 1.f / (1.f + expf(-decay[n]));
  int slot = -1;
  for (int j = 0; j < 256; ++j) if (swi[j] == n) { slot = j; break; }  // uniform
  float u;
  if (slot >= 0) {
    u = mem2u[(size_t)(b * 256 + slot) * DD + d];
  } else {
    float v = mem[((size_t)b * NN + n) * DD + d] + 1e-8f;
    float S = brsum128(v * v, sred, d);
    u = v / fmaxf(sqrtf(S), 1e-12f);
  }
  int h = rem >> 5;
  atomicAdd(&rph[(b * HH + h) * DD + d], w * sc * u);
}

// ---- K7: merge matvec + LayerNorm -> out (512 threads, split-K) ----
__global__ __launch_bounds__(512) void k7_merge(
    const float* __restrict__ rph, const float* __restrict__ W_merge,
    const float* __restrict__ b_merge, const float* __restrict__ ln_g,
    const float* __restrict__ ln_b, float* __restrict__ out) {
  int b = blockIdx.x;
  int tid = threadIdx.x;
  int d = tid & 127;
  int p = tid >> 7;              // 0..3
  __shared__ float acc_s[4][DD];
  __shared__ float accf[DD];
  __shared__ float smu, svar;

  float a = 0.f;
  int j0 = p * 256;
  #pragma unroll 4
  for (int j = j0; j < j0 + 256; ++j)
    a += rph[b * HH * DD + j] * W_merge[j * DD + d];
  acc_s[p][d] = a;
  __syncthreads();
  if (tid < DD) accf[d] = b_merge[d] + acc_s[0][d] + acc_s[1][d] + acc_s[2][d] + acc_s[3][d];
  __syncthreads();
  if (tid < 64) {
    float x0 = accf[tid], x1 = accf[tid + 64];
    float s1 = x0 + x1, s2 = x0 * x0 + x1 * x1;
    #pragma unroll
    for (int o = 32; o > 0; o >>= 1) { s1 += __shfl_xor(s1, o); s2 += __shfl_xor(s2, o); }
    if (tid == 0) { smu = s1 * (1.f / DD); svar = s2 * (1.f / DD) - smu * smu; }
  }
  __syncthreads();
  if (tid < DD)
    out[b * DD + d] = (accf[d] - smu) * rsqrtf(svar + 1e-5f) * ln_g[d] + ln_b[d];
}

extern "C" void kernel_launch(void* const* d_in, const int* in_sizes, int n_in,
                              void* d_out, int out_size, void* d_ws, size_t ws_size,
                              hipStream_t stream) {
  const float* memory  = (const float*)d_in[0];
  const float* rkeys   = (const float*)d_in[1];
  const float* wkeys   = (const float*)d_in[2];
  const float* wvals   = (const float*)d_in[3];
  const float* erase   = (const float*)d_in[4];
  const float* adg     = (const float*)d_in[5];
  const float* beta_r  = (const float*)d_in[6];
  const float* beta_w  = (const float*)d_in[7];
  const float* W_b1    = (const float*)d_in[8];
  const float* b_b1    = (const float*)d_in[9];
  const float* W_b2    = (const float*)d_in[10];
  const float* b_b2    = (const float*)d_in[11];
  const float* W_merge = (const float*)d_in[12];
  const float* b_merge = (const float*)d_in[13];
  const float* ln_g    = (const float*)d_in[14];
  const float* ln_b    = (const float*)d_in[15];
  const float* decay   = (const float*)d_in[16];

  float* ws   = (float*)d_ws;        // needs ~35 MB
  float* simw = ws + OFF_SIMW;
  float* simr = ws + OFF_SIMR;
  float* nwk  = ws + OFF_NWK;
  float* nrk  = ws + OFF_NRK;
  float* cv   = ws + OFF_CV;
  int*   widx = (int*)(ws + OFF_WIDX);
  float* wval = ws + OFF_WVAL;
  int*   ridx = (int*)(ws + OFF_RIDX);
  float* rval = ws + OFF_RVAL;
  float* m2u  = ws + OFF_M2U;
  float* rph  = ws + OFF_RPH;

  hipLaunchKernelGGL(k1_setup, dim3(BB * HH), dim3(128), 0, stream,
                     wkeys, rkeys, wvals, beta_r, beta_w, W_b1, b_b1, W_b2, b_b2,
                     nwk, nrk, cv, rph);
  hipLaunchKernelGGL(k2_sims, dim3(BB * (NN / 256)), dim3(256), 0, stream,
                     memory, nwk, nrk, simw, simr);
  hipLaunchKernelGGL(k_topk, dim3(BB * HH), dim3(1024), 0, stream, simw, widx, wval);
  hipLaunchKernelGGL(k4_write, dim3(BB * 256), dim3(128), 0, stream,
                     memory, erase, adg, widx, wval, cv, nrk, m2u, simr);
  hipLaunchKernelGGL(k_topk, dim3(BB * HH), dim3(1024), 0, stream, simr, ridx, rval);
  hipLaunchKernelGGL(k6_gather, dim3(BB * 256), dim3(128), 0, stream,
                     memory, decay, widx, ridx, rval, m2u, rph);
  hipLaunchKernelGGL(k7_merge, dim3(BB), dim3(512), 0, stream,
                     rph, W_merge, b_merge, ln_g, ln_b, (float*)d_out);
}

// Round 4
// 599.701 us; speedup vs baseline: 1.2832x; 1.2832x over previous
//
#include <hip/hip_runtime.h>
#include <hip/hip_bf16.h>

// Problem constants (match reference)
#define BB   8
#define HH   8
#define NN   65536
#define DD   128
#define BDIM 64
#define KK   32

// All inputs/outputs are float32 per the reference dtypes.

// Workspace layout (float units)
#define OFF_SIMW 0u                       // B*H*N = 4194304
#define OFF_SIMR (OFF_SIMW + 4194304u)    // 4194304
#define OFF_NWK  (OFF_SIMR + 4194304u)    // 8192
#define OFF_NRK  (OFF_NWK + 8192u)        // 8192
#define OFF_CV   (OFF_NRK + 8192u)        // 8192
#define OFF_WIDX (OFF_CV + 8192u)         // 2048 (int)
#define OFF_WVAL (OFF_WIDX + 2048u)       // 2048
#define OFF_RIDX (OFF_WVAL + 2048u)       // 2048 (int)
#define OFF_RVAL (OFF_RIDX + 2048u)       // 2048
#define OFF_M2U  (OFF_RVAL + 2048u)       // B*256*D = 262144
#define OFF_RPH  (OFF_M2U + 262144u)      // 8192
// total = 8691712 floats = ~34.8 MB

// ---- helpers ----
__device__ __forceinline__ float brsum128(float v, float* sred, int tid) {
  #pragma unroll
  for (int o = 32; o > 0; o >>= 1) v += __shfl_xor(v, o);
  __syncthreads();
  if ((tid & 63) == 0) sred[tid >> 6] = v;
  __syncthreads();
  return sred[0] + sred[1];
}

// ---- K1: normalize keys (fold beta), MLP cvals, zero rph ----
__global__ __launch_bounds__(128) void k1_setup(
    const float* __restrict__ wkeys, const float* __restrict__ rkeys,
    const float* __restrict__ wvals,
    const float* __restrict__ beta_r, const float* __restrict__ beta_w,
    const float* __restrict__ W_b1, const float* __restrict__ b_b1,
    const float* __restrict__ W_b2, const float* __restrict__ b_b2,
    float* __restrict__ nwk, float* __restrict__ nrk,
    float* __restrict__ cvals, float* __restrict__ rph) {
  int g = blockIdx.x;      // b*H + h, 0..63
  int d = threadIdx.x;     // 0..127
  __shared__ float sred[2];
  __shared__ float wv_s[DD];
  __shared__ float hid[BDIM];

  rph[g * DD + d] = 0.f;

  float wk = wkeys[g * DD + d];
  float rk = rkeys[g * DD + d];
  float wv = wvals[g * DD + d];
  wv_s[d] = wv;

  float s = brsum128(wk * wk, sred, d);
  nwk[g * DD + d] = wk / fmaxf(sqrtf(s), 1e-12f) * beta_w[g];
  s = brsum128(rk * rk, sred, d);
  nrk[g * DD + d] = rk / fmaxf(sqrtf(s), 1e-12f) * beta_r[g];

  __syncthreads();
  if (d < BDIM) {
    float a = b_b1[d];
    #pragma unroll 4
    for (int dd = 0; dd < DD; ++dd) a += wv_s[dd] * W_b1[dd * BDIM + d];
    hid[d] = a * 0.5f * (1.f + erff(a * 0.70710678118654752f));  // exact gelu
  }
  __syncthreads();
  float c = b_b2[d];
  #pragma unroll 4
  for (int j = 0; j < BDIM; ++j) c += hid[j] * W_b2[j * DD + d];
  cvals[g * DD + d] = c;
}

// ---- K2: big pass over memory: row norms + 16 dots -> simw, simr ----
// Per-lane row streaming; cached loads (NT was a 3x over-fetch: 739MB vs
// 268MB ideal, measured). Explicit double-buffer: load 128B group g+1
// while computing group g so HBM latency hides under the 8h dot FMAs.
__global__ __launch_bounds__(256) void k2_sims(
    const float* __restrict__ mem,
    const float* __restrict__ nwk, const float* __restrict__ nrk,
    float* __restrict__ simw, float* __restrict__ simr) {
  int blk = blockIdx.x;          // 0..2047
  int b   = blk >> 8;
  int n   = ((blk & 255) << 8) + threadIdx.x;   // row in [0,N)
  const float4* rowp = (const float4*)(mem + ((size_t)b * NN + n) * DD);

  float dw[HH] = {0,0,0,0,0,0,0,0};
  float dr[HH] = {0,0,0,0,0,0,0,0};
  float nw = 0.f, nr = 0.f;
  const float* kw = nwk + b * HH * DD;   // block-uniform -> scalar loads
  const float* kr = nrk + b * HH * DD;

  float4 q[8], p[8];
  #pragma unroll
  for (int i = 0; i < 8; ++i) q[i] = rowp[i];
  #pragma unroll
  for (int g = 0; g < 4; ++g) {          // 4 groups x 128B
    if (g < 3) {
      #pragma unroll
      for (int i = 0; i < 8; ++i) p[i] = rowp[(g + 1) * 8 + i];
    }
    #pragma unroll
    for (int i = 0; i < 8; ++i) {
      float xs[4] = {q[i].x, q[i].y, q[i].z, q[i].w};
      #pragma unroll
      for (int e = 0; e < 4; ++e) {
        float xv = xs[e];
        float xr = xv + 1e-8f;
        nw += xv * xv;
        nr += xr * xr;
        int d = g * 32 + i * 4 + e;
        #pragma unroll
        for (int h = 0; h < HH; ++h) {
          dw[h] += xv * kw[h * DD + d];
          dr[h] += xr * kr[h * DD + d];
        }
      }
    }
    #pragma unroll
    for (int i = 0; i < 8; ++i) q[i] = p[i];   // renamed away by regalloc
  }
  float riw = 1.f / fmaxf(sqrtf(nw), 1e-12f);
  float rir = 1.f / fmaxf(sqrtf(nr), 1e-12f);
  #pragma unroll
  for (int h = 0; h < HH; ++h) {
    simw[(size_t)(b * HH + h) * NN + n] = dw[h] * riw;
    simr[(size_t)(b * HH + h) * NN + n] = dr[h] * rir;
  }
}

// ---- K3/K5: exact top-32 + softmax via exponent-bucket histogram select ----
// Bucket = top 12 bits of the ordered-float bit pattern (sign+exp+3
// mantissa): monotonic + scale-invariant, no min/max pass needed.
// Pass A histograms only a 1/8 PREFIX SAMPLE (8192 values): since the
// sample is a subset, cum_sample >= K at the threshold bucket implies
// full count >= K, so pass B's candidates are still a superset of the
// true top-32 (expected nc ~ 250 for Gaussian sims). 8x fewer LDS
// atomics and 8x fewer pass-A reads.
#define NBKT 4096
#define MAXC 4096
#define SAMP 2048   // float4s sampled in pass A (of NN/4 = 16384)
__global__ __launch_bounds__(1024) void k_topk(
    const float* __restrict__ sims, int* __restrict__ oidx, float* __restrict__ oval) {
  int blk = blockIdx.x;          // (b*H+h), 0..63
  int tid = threadIdx.x;
  const float4* s4 = (const float4*)(sims + (size_t)blk * NN);
  __shared__ unsigned hist[NBKT];
  __shared__ unsigned segsum[64];
  __shared__ float cv[MAXC];
  __shared__ int   ci[MAXC];
  __shared__ int   sthr, scnt;
  __shared__ float selv[KK];
  __shared__ int   seli[KK];

  #pragma unroll
  for (int i = tid; i < NBKT; i += 1024) hist[i] = 0u;
  if (tid == 0) scnt = 0;
  __syncthreads();

  // pass A: sampled histogram on ordered-float top-12-bit buckets
  #pragma unroll
  for (int i = tid; i < SAMP; i += 1024) {
    float4 v = s4[i];
    float xs[4] = {v.x, v.y, v.z, v.w};
    #pragma unroll
    for (int e = 0; e < 4; ++e) {
      unsigned u = __float_as_uint(xs[e]);
      u = (u & 0x80000000u) ? ~u : (u | 0x80000000u);
      atomicAdd(&hist[u >> 20], 1u);
    }
  }
  __syncthreads();

  // threshold: cumulative count from the top; two-level scan.
  // rotated reads: lane t reads hist[t*64 + ((j+t)&63)] -> all banks hit,
  // avoids the 64-way conflict of straight stride-64 segment sums.
  if (tid < 64) {
    unsigned ssum = 0;
    int base = tid << 6;
    #pragma unroll
    for (int j = 0; j < 64; ++j) ssum += hist[base + ((j + tid) & 63)];
    segsum[tid] = ssum;
  }
  __syncthreads();
  if (tid == 0) {
    unsigned acc = 0;
    int sg = 63;
    while (sg > 0 && acc + segsum[sg] < KK) { acc += segsum[sg]; --sg; }
    int t = (sg << 6) + 63;
    while (t > (sg << 6) && acc + hist[t] < KK) { acc += hist[t]; --t; }
    sthr = t;
  }
  __syncthreads();

  // pass B: compact candidates (bucket >= threshold -> superset of top-32)
  int thr = sthr;
  #pragma unroll 2
  for (int i = tid; i < NN / 4; i += 1024) {
    float4 v = s4[i];
    float xs[4] = {v.x, v.y, v.z, v.w};
    #pragma unroll
    for (int e = 0; e < 4; ++e) {
      float vv = xs[e];
      unsigned u = __float_as_uint(vv);
      u = (u & 0x80000000u) ? ~u : (u | 0x80000000u);
      if ((int)(u >> 20) >= thr) {
        int p = atomicAdd(&scnt, 1);
        if (p < MAXC) { cv[p] = vv; ci[p] = i * 4 + e; }
      }
    }
  }
  __syncthreads();
  int nc = min(scnt, MAXC);

  // 32 exact extractions by wave 0 only: 64-bit key = (ordered(v) << 32) | ~idx
  // (value desc, index asc — matches lax.top_k), shuffle-reduced, no barriers.
  if (tid < 64) {
    for (int k = 0; k < KK; ++k) {
      unsigned long long best = 0ull, lbest = 0ull;
      int lj = -1;
      for (int j = tid; j < nc; j += 64) {
        float v = cv[j];
        unsigned u = __float_as_uint(v);
        u = (u & 0x80000000u) ? ~u : (u | 0x80000000u);
        unsigned long long key = ((unsigned long long)u << 32) | (unsigned)(~(unsigned)ci[j]);
        if (key > lbest) { lbest = key; lj = j; }
      }
      best = lbest;
      #pragma unroll
      for (int o = 32; o > 0; o >>= 1) {
        unsigned long long t = __shfl_xor(best, o);
        if (t > best) best = t;
      }
      if (lbest == best && lj >= 0) cv[lj] = -1e30f;   // owner removes winner
      if (tid == 0) {
        unsigned u = (unsigned)(best >> 32);
        float v = (u & 0x80000000u) ? __uint_as_float(u & 0x7fffffffu) : __uint_as_float(~u);
        selv[k] = v;
        seli[k] = (int)~(unsigned)(best & 0xffffffffu);
      }
    }
    if (tid == 0) {
      float m0 = selv[0], ssum = 0.f;   // selv descending -> selv[0] is max
      float es[KK];
      #pragma unroll
      for (int k = 0; k < KK; ++k) { es[k] = expf(selv[k] - m0); ssum += es[k]; }
      float inv = 1.f / ssum;
      #pragma unroll
      for (int k = 0; k < KK; ++k) {
        oidx[blk * KK + k] = seli[k];
        oval[blk * KK + k] = es[k] * inv;
      }
    }
  }
}

// ---- K4: apply erase/add to touched rows, store unit rows, patch simr ----
__global__ __launch_bounds__(128) void k4_write(
    const float* __restrict__ mem, const float* __restrict__ erase,
    const float* __restrict__ adg,
    const int* __restrict__ widx, const float* __restrict__ wval,
    const float* __restrict__ cvals, const float* __restrict__ nrk,
    float* __restrict__ mem2u, float* __restrict__ simr) {
  int b  = blockIdx.x >> 8;
  int sl = blockIdx.x & 255;          // slot in b's write list (h*32+k)
  int d  = threadIdx.x;
  __shared__ int   swi[256];
  __shared__ float swv[256];
  __shared__ float sred[2 * 9];

  swi[d]       = widx[b * 256 + d];
  swi[d + 128] = widx[b * 256 + d + 128];
  swv[d]       = wval[b * 256 + d];
  swv[d + 128] = wval[b * 256 + d + 128];
  __syncthreads();

  int n = swi[sl];
  for (int j = 0; j < sl; ++j) if (swi[j] == n) return;  // uniform: whole block

  float E = 0.f, addd = 0.f;
  #pragma unroll
  for (int h = 0; h < HH; ++h) {
    float er = erase[b * HH + h];
    float ag = adg[b * HH + h];
    float aw = 0.f;
    #pragma unroll 4
    for (int k = 0; k < KK; ++k) {
      int j = h * KK + k;
      if (swi[j] == n) { float wv = swv[j]; E += wv * er; aw += wv; }
    }
    addd += aw * ag * cvals[(b * HH + h) * DD + d];
  }
  float mval = mem[((size_t)b * NN + n) * DD + d];
  float v = mval * (1.f - E * 0.125f) + addd * 0.125f + 1e-8f;

  // one fused 9-value reduction: [0]=v^2, [1..8]=nrk_h[d]*v
  float r[9];
  r[0] = v * v;
  #pragma unroll
  for (int h = 0; h < HH; ++h) r[1 + h] = nrk[(b * HH + h) * DD + d] * v;
  #pragma unroll
  for (int o = 32; o > 0; o >>= 1) {
    #pragma unroll
    for (int i = 0; i < 9; ++i) r[i] += __shfl_xor(r[i], o);
  }
  if ((d & 63) == 0) {
    int w = d >> 6;
    #pragma unroll
    for (int i = 0; i < 9; ++i) sred[w * 9 + i] = r[i];
  }
  __syncthreads();
  float S    = sred[0] + sred[9];
  float rinv = 1.f / fmaxf(sqrtf(S), 1e-12f);
  mem2u[(size_t)(b * 256 + sl) * DD + d] = v * rinv;
  if (d < HH) simr[(size_t)(b * HH + d) * NN + n] = (sred[1 + d] + sred[9 + 1 + d]) * rinv;
}

// ---- K6: gather read rows -> rph (atomic accumulate) ----
__global__ __launch_bounds__(128) void k6_gather(
    const float* __restrict__ mem, const float* __restrict__ decay,
    const int* __restrict__ widx, const int* __restrict__ ridx,
    const float* __restrict__ rval, const float* __restrict__ mem2u,
    float* __restrict__ rph) {
  int b   = blockIdx.x >> 8;
  int rem = blockIdx.x & 255;    // h*32+k
  int d   = threadIdx.x;
  __shared__ int swi[256];
  __shared__ float sred[2];
  swi[d]       = widx[b * 256 + d];
  swi[d + 128] = widx[b * 256 + d + 128];
  __syncthreads();

  int n   = ridx[b * HH * KK + rem];
  float w = rval[b * HH * KK + rem];
  float sc = 1.f / (1.f + expf(-decay[n]));
  int slot = -1;
  for (int j = 0; j < 256; ++j) if (swi[j] == n) { slot = j; break; }  // uniform
  float u;
  if (slot >= 0) {
    u = mem2u[(size_t)(b * 256 + slot) * DD + d];
  } else {
    float v = mem[((size_t)b * NN + n) * DD + d] + 1e-8f;
    float S = brsum128(v * v, sred, d);
    u = v / fmaxf(sqrtf(S), 1e-12f);
  }
  int h = rem >> 5;
  atomicAdd(&rph[(b * HH + h) * DD + d], w * sc * u);
}

// ---- K7: merge matvec + LayerNorm -> out (512 threads, split-K) ----
__global__ __launch_bounds__(512) void k7_merge(
    const float* __restrict__ rph, const float* __restrict__ W_merge,
    const float* __restrict__ b_merge, const float* __restrict__ ln_g,
    const float* __restrict__ ln_b, float* __restrict__ out) {
  int b = blockIdx.x;
  int tid = threadIdx.x;
  int d = tid & 127;
  int p = tid >> 7;              // 0..3
  __shared__ float acc_s[4][DD];
  __shared__ float accf[DD];
  __shared__ float smu, svar;

  float a = 0.f;
  int j0 = p * 256;
  #pragma unroll 4
  for (int j = j0; j < j0 + 256; ++j)
    a += rph[b * HH * DD + j] * W_merge[j * DD + d];
  acc_s[p][d] = a;
  __syncthreads();
  if (tid < DD) accf[d] = b_merge[d] + acc_s[0][d] + acc_s[1][d] + acc_s[2][d] + acc_s[3][d];
  __syncthreads();
  if (tid < 64) {
    float x0 = accf[tid], x1 = accf[tid + 64];
    float s1 = x0 + x1, s2 = x0 * x0 + x1 * x1;
    #pragma unroll
    for (int o = 32; o > 0; o >>= 1) { s1 += __shfl_xor(s1, o); s2 += __shfl_xor(s2, o); }
    if (tid == 0) { smu = s1 * (1.f / DD); svar = s2 * (1.f / DD) - smu * smu; }
  }
  __syncthreads();
  if (tid < DD)
    out[b * DD + d] = (accf[d] - smu) * rsqrtf(svar + 1e-5f) * ln_g[d] + ln_b[d];
}

extern "C" void kernel_launch(void* const* d_in, const int* in_sizes, int n_in,
                              void* d_out, int out_size, void* d_ws, size_t ws_size,
                              hipStream_t stream) {
  const float* memory  = (const float*)d_in[0];
  const float* rkeys   = (const float*)d_in[1];
  const float* wkeys   = (const float*)d_in[2];
  const float* wvals   = (const float*)d_in[3];
  const float* erase   = (const float*)d_in[4];
  const float* adg     = (const float*)d_in[5];
  const float* beta_r  = (const float*)d_in[6];
  const float* beta_w  = (const float*)d_in[7];
  const float* W_b1    = (const float*)d_in[8];
  const float* b_b1    = (const float*)d_in[9];
  const float* W_b2    = (const float*)d_in[10];
  const float* b_b2    = (const float*)d_in[11];
  const float* W_merge = (const float*)d_in[12];
  const float* b_merge = (const float*)d_in[13];
  const float* ln_g    = (const float*)d_in[14];
  const float* ln_b    = (const float*)d_in[15];
  const float* decay   = (const float*)d_in[16];

  float* ws   = (float*)d_ws;        // needs ~35 MB
  float* simw = ws + OFF_SIMW;
  float* simr = ws + OFF_SIMR;
  float* nwk  = ws + OFF_NWK;
  float* nrk  = ws + OFF_NRK;
  float* cv   = ws + OFF_CV;
  int*   widx = (int*)(ws + OFF_WIDX);
  float* wval = ws + OFF_WVAL;
  int*   ridx = (int*)(ws + OFF_RIDX);
  float* rval = ws + OFF_RVAL;
  float* m2u  = ws + OFF_M2U;
  float* rph  = ws + OFF_RPH;

  hipLaunchKernelGGL(k1_setup, dim3(BB * HH), dim3(128), 0, stream,
                     wkeys, rkeys, wvals, beta_r, beta_w, W_b1, b_b1, W_b2, b_b2,
                     nwk, nrk, cv, rph);
  hipLaunchKernelGGL(k2_sims, dim3(BB * (NN / 256)), dim3(256), 0, stream,
                     memory, nwk, nrk, simw, simr);
  hipLaunchKernelGGL(k_topk, dim3(BB * HH), dim3(1024), 0, stream, simw, widx, wval);
  hipLaunchKernelGGL(k4_write, dim3(BB * 256), dim3(128), 0, stream,
                     memory, erase, adg, widx, wval, cv, nrk, m2u, simr);
  hipLaunchKernelGGL(k_topk, dim3(BB * HH), dim3(1024), 0, stream, simr, ridx, rval);
  hipLaunchKernelGGL(k6_gather, dim3(BB * 256), dim3(128), 0, stream,
                     memory, decay, widx, ridx, rval, m2u, rph);
  hipLaunchKernelGGL(k7_merge, dim3(BB), dim3(512), 0, stream,
                     rph, W_merge, b_merge, ln_g, ln_b, (float*)d_out);
}

// Round 6
// 588.064 us; speedup vs baseline: 1.3086x; 1.0198x over previous
//
#include <hip/hip_runtime.h>
#include <hip/hip_bf16.h>

// Problem constants (match reference)
#define BB   8
#define HH   8
#define NN   65536
#define DD   128
#define BDIM 64
#define KK   32

// All inputs/outputs are float32 per the reference dtypes.

// Workspace layout (float units)
#define OFF_SIMW 0u                       // B*H*N = 4194304
#define OFF_SIMR (OFF_SIMW + 4194304u)    // 4194304
#define OFF_NWK  (OFF_SIMR + 4194304u)    // 8192
#define OFF_NRK  (OFF_NWK + 8192u)        // 8192
#define OFF_CV   (OFF_NRK + 8192u)        // 8192
#define OFF_WIDX (OFF_CV + 8192u)         // 2048 (int)
#define OFF_WVAL (OFF_WIDX + 2048u)       // 2048
#define OFF_RIDX (OFF_WVAL + 2048u)       // 2048 (int)
#define OFF_RVAL (OFF_RIDX + 2048u)       // 2048
#define OFF_M2U  (OFF_RVAL + 2048u)       // B*256*D = 262144
#define OFF_RPH  (OFF_M2U + 262144u)      // 8192
#define OFF_CVA  (OFF_RPH + 8192u)        // 1024*32 candidate vals
#define OFF_CIA  (OFF_CVA + 32768u)       // 1024*32 candidate idx (int)
// total = 8757248 floats = ~35.0 MB

// ---- helpers ----
__device__ __forceinline__ float brsum128(float v, float* sred, int tid) {
  #pragma unroll
  for (int o = 32; o > 0; o >>= 1) v += __shfl_xor(v, o);
  __syncthreads();
  if ((tid & 63) == 0) sred[tid >> 6] = v;
  __syncthreads();
  return sred[0] + sred[1];
}

__device__ __forceinline__ unsigned ordf(float v) {
  unsigned u = __float_as_uint(v);
  return (u & 0x80000000u) ? ~u : (u | 0x80000000u);
}
__device__ __forceinline__ float unordf(unsigned u) {
  return (u & 0x80000000u) ? __uint_as_float(u & 0x7fffffffu) : __uint_as_float(~u);
}

// ---- K1: normalize keys (fold beta), MLP cvals, zero rph ----
__global__ __launch_bounds__(128) void k1_setup(
    const float* __restrict__ wkeys, const float* __restrict__ rkeys,
    const float* __restrict__ wvals,
    const float* __restrict__ beta_r, const float* __restrict__ beta_w,
    const float* __restrict__ W_b1, const float* __restrict__ b_b1,
    const float* __restrict__ W_b2, const float* __restrict__ b_b2,
    float* __restrict__ nwk, float* __restrict__ nrk,
    float* __restrict__ cvals, float* __restrict__ rph) {
  int g = blockIdx.x;      // b*H + h, 0..63
  int d = threadIdx.x;     // 0..127
  __shared__ float sred[2];
  __shared__ float wv_s[DD];
  __shared__ float hid[BDIM];

  rph[g * DD + d] = 0.f;

  float wk = wkeys[g * DD + d];
  float rk = rkeys[g * DD + d];
  float wv = wvals[g * DD + d];
  wv_s[d] = wv;

  float s = brsum128(wk * wk, sred, d);
  nwk[g * DD + d] = wk / fmaxf(sqrtf(s), 1e-12f) * beta_w[g];
  s = brsum128(rk * rk, sred, d);
  nrk[g * DD + d] = rk / fmaxf(sqrtf(s), 1e-12f) * beta_r[g];

  __syncthreads();
  if (d < BDIM) {
    float a = b_b1[d];
    #pragma unroll 4
    for (int dd = 0; dd < DD; ++dd) a += wv_s[dd] * W_b1[dd * BDIM + d];
    hid[d] = a * 0.5f * (1.f + erff(a * 0.70710678118654752f));  // exact gelu
  }
  __syncthreads();
  float c = b_b2[d];
  #pragma unroll 4
  for (int j = 0; j < BDIM; ++j) c += hid[j] * W_b2[j * DD + d];
  cvals[g * DD + d] = c;
}

// ---- K2: big pass over memory: row norms + 16 dots -> simw, simr ----
// Per-lane row streaming; cached loads (NT was a 3x over-fetch: 739MB vs
// 268MB ideal, measured). Explicit double-buffer: load 128B group g+1
// while computing group g so HBM latency hides under the 8h dot FMAs.
__global__ __launch_bounds__(256) void k2_sims(
    const float* __restrict__ mem,
    const float* __restrict__ nwk, const float* __restrict__ nrk,
    float* __restrict__ simw, float* __restrict__ simr) {
  int blk = blockIdx.x;          // 0..2047
  int b   = blk >> 8;
  int n   = ((blk & 255) << 8) + threadIdx.x;   // row in [0,N)
  const float4* rowp = (const float4*)(mem + ((size_t)b * NN + n) * DD);

  float dw[HH] = {0,0,0,0,0,0,0,0};
  float dr[HH] = {0,0,0,0,0,0,0,0};
  float nw = 0.f, nr = 0.f;
  const float* kw = nwk + b * HH * DD;   // block-uniform -> scalar loads
  const float* kr = nrk + b * HH * DD;

  float4 q[8], p[8];
  #pragma unroll
  for (int i = 0; i < 8; ++i) q[i] = rowp[i];
  #pragma unroll
  for (int g = 0; g < 4; ++g) {          // 4 groups x 128B
    if (g < 3) {
      #pragma unroll
      for (int i = 0; i < 8; ++i) p[i] = rowp[(g + 1) * 8 + i];
    }
    #pragma unroll
    for (int i = 0; i < 8; ++i) {
      float xs[4] = {q[i].x, q[i].y, q[i].z, q[i].w};
      #pragma unroll
      for (int e = 0; e < 4; ++e) {
        float xv = xs[e];
        float xr = xv + 1e-8f;
        nw += xv * xv;
        nr += xr * xr;
        int d = g * 32 + i * 4 + e;
        #pragma unroll
        for (int h = 0; h < HH; ++h) {
          dw[h] += xv * kw[h * DD + d];
          dr[h] += xr * kr[h * DD + d];
        }
      }
    }
    #pragma unroll
    for (int i = 0; i < 8; ++i) q[i] = p[i];   // renamed away by regalloc
  }
  float riw = 1.f / fmaxf(sqrtf(nw), 1e-12f);
  float rir = 1.f / fmaxf(sqrtf(nr), 1e-12f);
  #pragma unroll
  for (int h = 0; h < HH; ++h) {
    simw[(size_t)(b * HH + h) * NN + n] = dw[h] * riw;
    simr[(size_t)(b * HH + h) * NN + n] = dr[h] * rir;
  }
}

// ---- hierarchical exact top-32 ----
// Old single-block topk was latency-bound: 64 blocks (25% of CUs, 1/CU)
// scanning 256KB each from LLC. Stage 1 spreads the scan over 1024 blocks
// (16 chunks x 64 rows, 16KB each): exp-bucket histogram -> threshold ->
// compact (superset of chunk top-32) -> exact local top-32 by 64-bit key.
// Stage 2 merges 16x32=512 candidates per (b,h) in registers (exact).
// Key = (ordered(v)<<32) | ~idx: value desc, index asc == lax.top_k order.
#define TKCH  16              // chunks per (b,h) row
#define CHLEN (NN / TKCH)     // 4096 values per chunk
#define MAXCL 1024            // candidate cap (expected ~90 for Gaussian)

__global__ __launch_bounds__(256) void k_topk_local(
    const float* __restrict__ sims, float* __restrict__ cval, int* __restrict__ cidx) {
  int blk = blockIdx.x;           // bh*TKCH + chunk
  int bh  = blk >> 4;
  int ch  = blk & 15;
  int tid = threadIdx.x;
  const float4* s4 = (const float4*)(sims + (size_t)bh * NN + ch * CHLEN);
  __shared__ unsigned hist[4096];
  __shared__ unsigned segsum[64];
  __shared__ float cv[MAXCL];
  __shared__ int   ci[MAXCL];
  __shared__ int   sthr, scnt;

  #pragma unroll
  for (int i = tid; i < 4096; i += 256) hist[i] = 0u;
  if (tid == 0) scnt = 0;
  __syncthreads();

  // load this thread's 16 values (4 float4s), histogram their buckets
  float4 v[4];
  #pragma unroll
  for (int j = 0; j < 4; ++j) v[j] = s4[tid + j * 256];
  unsigned ub[16];
  #pragma unroll
  for (int j = 0; j < 4; ++j) {
    float xs[4] = {v[j].x, v[j].y, v[j].z, v[j].w};
    #pragma unroll
    for (int e = 0; e < 4; ++e) {
      unsigned u = ordf(xs[e]);
      ub[j * 4 + e] = u;
      atomicAdd(&hist[u >> 20], 1u);
    }
  }
  __syncthreads();

  // threshold: cumulative from top, two-level scan (rotated reads)
  if (tid < 64) {
    unsigned ssum = 0;
    int base = tid << 6;
    #pragma unroll
    for (int j = 0; j < 64; ++j) ssum += hist[base + ((j + tid) & 63)];
    segsum[tid] = ssum;
  }
  __syncthreads();
  if (tid == 0) {
    unsigned acc = 0;
    int sg = 63;
    while (sg > 0 && acc + segsum[sg] < KK) { acc += segsum[sg]; --sg; }
    int t = (sg << 6) + 63;
    while (t > (sg << 6) && acc + hist[t] < KK) { acc += hist[t]; --t; }
    sthr = t;
  }
  __syncthreads();

  // compact candidates (bucket >= thr -> superset of chunk top-32)
  int thr = sthr;
  #pragma unroll
  for (int j = 0; j < 16; ++j) {
    unsigned u = ub[j];
    if ((int)(u >> 20) >= thr) {
      int p = atomicAdd(&scnt, 1);
      if (p < MAXCL) {
        int li = (tid + (j >> 2) * 256) * 4 + (j & 3);   // idx within chunk
        cv[p] = unordf(u);
        ci[p] = ch * CHLEN + li;
      }
    }
  }
  __syncthreads();
  int nc = min(scnt, MAXCL);

  // exact local top-32 by wave 0
  if (tid < 64) {
    for (int k = 0; k < KK; ++k) {
      unsigned long long lbest = 0ull;
      int lj = -1;
      for (int j = tid; j < nc; j += 64) {
        unsigned long long key = ((unsigned long long)ordf(cv[j]) << 32) |
                                 (unsigned)(~(unsigned)ci[j]);
        if (key > lbest) { lbest = key; lj = j; }
      }
      unsigned long long best = lbest;
      #pragma unroll
      for (int o = 32; o > 0; o >>= 1) {
        unsigned long long t = __shfl_xor(best, o);
        if (t > best) best = t;
      }
      if (lbest == best && lj >= 0) cv[lj] = -1e30f;   // owner removes winner (LDS, ok)
      if (tid == 0) {
        cval[blk * KK + k] = unordf((unsigned)(best >> 32));
        cidx[blk * KK + k] = (int)~(unsigned)(best & 0xffffffffu);
      }
    }
  }
}

// Stage 2: merge 512 candidates per (b,h): 8 keys/lane in registers,
// 32 shuffle-reduce rounds. Winner removal is branchless compare-and-zero
// (keys unique since idx unique) — NO dynamic register indexing (the
// key[lj] form with runtime lj segfaulted clang-22's unroller).
__global__ __launch_bounds__(64) void k_topk_merge(
    const float* __restrict__ cval, const int* __restrict__ cidx,
    int* __restrict__ oidx, float* __restrict__ oval) {
  int bh   = blockIdx.x;    // 0..63
  int lane = threadIdx.x;   // 0..63
  __shared__ float selv[KK];
  __shared__ int   seli[KK];
  unsigned long long key[8];
  #pragma unroll
  for (int j = 0; j < 8; ++j) {
    int i = lane + j * 64;                       // 0..511
    float v  = cval[bh * (TKCH * KK) + i];
    int   id = cidx[bh * (TKCH * KK) + i];
    key[j] = ((unsigned long long)ordf(v) << 32) | (unsigned)(~(unsigned)id);
  }
  for (int k = 0; k < KK; ++k) {
    unsigned long long best = 0ull;
    #pragma unroll
    for (int j = 0; j < 8; ++j) best = (key[j] > best) ? key[j] : best;
    #pragma unroll
    for (int o = 32; o > 0; o >>= 1) {
      unsigned long long t = __shfl_xor(best, o);
      if (t > best) best = t;
    }
    #pragma unroll
    for (int j = 0; j < 8; ++j) key[j] = (key[j] == best) ? 0ull : key[j];
    if (lane == 0) {
      selv[k] = unordf((unsigned)(best >> 32));
      seli[k] = (int)~(unsigned)(best & 0xffffffffu);
    }
  }
  // single wave: lane 0's LDS writes are visible to itself; softmax on lane 0
  if (lane == 0) {
    float m0 = selv[0], ssum = 0.f;    // selv descending -> selv[0] is max
    float es[KK];
    #pragma unroll
    for (int k = 0; k < KK; ++k) { es[k] = expf(selv[k] - m0); ssum += es[k]; }
    float inv = 1.f / ssum;
    #pragma unroll
    for (int k = 0; k < KK; ++k) {
      oidx[bh * KK + k] = seli[k];
      oval[bh * KK + k] = es[k] * inv;
    }
  }
}

// ---- K4: apply erase/add to touched rows, store unit rows, patch simr ----
__global__ __launch_bounds__(128) void k4_write(
    const float* __restrict__ mem, const float* __restrict__ erase,
    const float* __restrict__ adg,
    const int* __restrict__ widx, const float* __restrict__ wval,
    const float* __restrict__ cvals, const float* __restrict__ nrk,
    float* __restrict__ mem2u, float* __restrict__ simr) {
  int b  = blockIdx.x >> 8;
  int sl = blockIdx.x & 255;          // slot in b's write list (h*32+k)
  int d  = threadIdx.x;
  __shared__ int   swi[256];
  __shared__ float swv[256];
  __shared__ float sred[2 * 9];

  swi[d]       = widx[b * 256 + d];
  swi[d + 128] = widx[b * 256 + d + 128];
  swv[d]       = wval[b * 256 + d];
  swv[d + 128] = wval[b * 256 + d + 128];
  __syncthreads();

  int n = swi[sl];
  for (int j = 0; j < sl; ++j) if (swi[j] == n) return;  // uniform: whole block

  float E = 0.f, addd = 0.f;
  #pragma unroll
  for (int h = 0; h < HH; ++h) {
    float er = erase[b * HH + h];
    float ag = adg[b * HH + h];
    float aw = 0.f;
    #pragma unroll 4
    for (int k = 0; k < KK; ++k) {
      int j = h * KK + k;
      if (swi[j] == n) { float wv = swv[j]; E += wv * er; aw += wv; }
    }
    addd += aw * ag * cvals[(b * HH + h) * DD + d];
  }
  float mval = mem[((size_t)b * NN + n) * DD + d];
  float v = mval * (1.f - E * 0.125f) + addd * 0.125f + 1e-8f;

  // one fused 9-value reduction: [0]=v^2, [1..8]=nrk_h[d]*v
  float r[9];
  r[0] = v * v;
  #pragma unroll
  for (int h = 0; h < HH; ++h) r[1 + h] = nrk[(b * HH + h) * DD + d] * v;
  #pragma unroll
  for (int o = 32; o > 0; o >>= 1) {
    #pragma unroll
    for (int i = 0; i < 9; ++i) r[i] += __shfl_xor(r[i], o);
  }
  if ((d & 63) == 0) {
    int w = d >> 6;
    #pragma unroll
    for (int i = 0; i < 9; ++i) sred[w * 9 + i] = r[i];
  }
  __syncthreads();
  float S    = sred[0] + sred[9];
  float rinv = 1.f / fmaxf(sqrtf(S), 1e-12f);
  mem2u[(size_t)(b * 256 + sl) * DD + d] = v * rinv;
  if (d < HH) simr[(size_t)(b * HH + d) * NN + n] = (sred[1 + d] + sred[9 + 1 + d]) * rinv;
}

// ---- K6: gather read rows -> rph (atomic accumulate) ----
__global__ __launch_bounds__(128) void k6_gather(
    const float* __restrict__ mem, const float* __restrict__ decay,
    const int* __restrict__ widx, const int* __restrict__ ridx,
    const float* __restrict__ rval, const float* __restrict__ mem2u,
    float* __restrict__ rph) {
  int b   = blockIdx.x >> 8;
  int rem = blockIdx.x & 255;    // h*32+k
  int d   = threadIdx.x;
  __shared__ int swi[256];
  __shared__ float sred[2];
  swi[d]       = widx[b * 256 + d];
  swi[d + 128] = widx[b * 256 + d + 128];
  __syncthreads();

  int n   = ridx[b * HH * KK + rem];
  float w = rval[b * HH * KK + rem];
  float sc = 1.f / (1.f + expf(-decay[n]));
  int slot = -1;
  for (int j = 0; j < 256; ++j) if (swi[j] == n) { slot = j; break; }  // uniform
  float u;
  if (slot >= 0) {
    u = mem2u[(size_t)(b * 256 + slot) * DD + d];
  } else {
    float v = mem[((size_t)b * NN + n) * DD + d] + 1e-8f;
    float S = brsum128(v * v, sred, d);
    u = v / fmaxf(sqrtf(S), 1e-12f);
  }
  int h = rem >> 5;
  atomicAdd(&rph[(b * HH + h) * DD + d], w * sc * u);
}

// ---- K7: merge matvec + LayerNorm -> out (512 threads, split-K) ----
__global__ __launch_bounds__(512) void k7_merge(
    const float* __restrict__ rph, const float* __restrict__ W_merge,
    const float* __restrict__ b_merge, const float* __restrict__ ln_g,
    const float* __restrict__ ln_b, float* __restrict__ out) {
  int b = blockIdx.x;
  int tid = threadIdx.x;
  int d = tid & 127;
  int p = tid >> 7;              // 0..3
  __shared__ float acc_s[4][DD];
  __shared__ float accf[DD];
  __shared__ float smu, svar;

  float a = 0.f;
  int j0 = p * 256;
  #pragma unroll 4
  for (int j = j0; j < j0 + 256; ++j)
    a += rph[b * HH * DD + j] * W_merge[j * DD + d];
  acc_s[p][d] = a;
  __syncthreads();
  if (tid < DD) accf[d] = b_merge[d] + acc_s[0][d] + acc_s[1][d] + acc_s[2][d] + acc_s[3][d];
  __syncthreads();
  if (tid < 64) {
    float x0 = accf[tid], x1 = accf[tid + 64];
    float s1 = x0 + x1, s2 = x0 * x0 + x1 * x1;
    #pragma unroll
    for (int o = 32; o > 0; o >>= 1) { s1 += __shfl_xor(s1, o); s2 += __shfl_xor(s2, o); }
    if (tid == 0) { smu = s1 * (1.f / DD); svar = s2 * (1.f / DD) - smu * smu; }
  }
  __syncthreads();
  if (tid < DD)
    out[b * DD + d] = (accf[d] - smu) * rsqrtf(svar + 1e-5f) * ln_g[d] + ln_b[d];
}

extern "C" void kernel_launch(void* const* d_in, const int* in_sizes, int n_in,
                              void* d_out, int out_size, void* d_ws, size_t ws_size,
                              hipStream_t stream) {
  const float* memory  = (const float*)d_in[0];
  const float* rkeys   = (const float*)d_in[1];
  const float* wkeys   = (const float*)d_in[2];
  const float* wvals   = (const float*)d_in[3];
  const float* erase   = (const float*)d_in[4];
  const float* adg     = (const float*)d_in[5];
  const float* beta_r  = (const float*)d_in[6];
  const float* beta_w  = (const float*)d_in[7];
  const float* W_b1    = (const float*)d_in[8];
  const float* b_b1    = (const float*)d_in[9];
  const float* W_b2    = (const float*)d_in[10];
  const float* b_b2    = (const float*)d_in[11];
  const float* W_merge = (const float*)d_in[12];
  const float* b_merge = (const float*)d_in[13];
  const float* ln_g    = (const float*)d_in[14];
  const float* ln_b    = (const float*)d_in[15];
  const float* decay   = (const float*)d_in[16];

  float* ws   = (float*)d_ws;        // needs ~35 MB
  float* simw = ws + OFF_SIMW;
  float* simr = ws + OFF_SIMR;
  float* nwk  = ws + OFF_NWK;
  float* nrk  = ws + OFF_NRK;
  float* cv   = ws + OFF_CV;
  int*   widx = (int*)(ws + OFF_WIDX);
  float* wval = ws + OFF_WVAL;
  int*   ridx = (int*)(ws + OFF_RIDX);
  float* rval = ws + OFF_RVAL;
  float* m2u  = ws + OFF_M2U;
  float* rph  = ws + OFF_RPH;
  float* cva  = ws + OFF_CVA;
  int*   cia  = (int*)(ws + OFF_CIA);

  hipLaunchKernelGGL(k1_setup, dim3(BB * HH), dim3(128), 0, stream,
                     wkeys, rkeys, wvals, beta_r, beta_w, W_b1, b_b1, W_b2, b_b2,
                     nwk, nrk, cv, rph);
  hipLaunchKernelGGL(k2_sims, dim3(BB * (NN / 256)), dim3(256), 0, stream,
                     memory, nwk, nrk, simw, simr);
  hipLaunchKernelGGL(k_topk_local, dim3(BB * HH * TKCH), dim3(256), 0, stream,
                     simw, cva, cia);
  hipLaunchKernelGGL(k_topk_merge, dim3(BB * HH), dim3(64), 0, stream,
                     cva, cia, widx, wval);
  hipLaunchKernelGGL(k4_write, dim3(BB * 256), dim3(128), 0, stream,
                     memory, erase, adg, widx, wval, cv, nrk, m2u, simr);
  hipLaunchKernelGGL(k_topk_local, dim3(BB * HH * TKCH), dim3(256), 0, stream,
                     simr, cva, cia);
  hipLaunchKernelGGL(k_topk_merge, dim3(BB * HH), dim3(64), 0, stream,
                     cva, cia, ridx, rval);
  hipLaunchKernelGGL(k6_gather, dim3(BB * 256), dim3(128), 0, stream,
                     memory, decay, widx, ridx, rval, m2u, rph);
  hipLaunchKernelGGL(k7_merge, dim3(BB), dim3(512), 0, stream,
                     rph, W_merge, b_merge, ln_g, ln_b, (float*)d_out);
}